// Round 5
// baseline (880.063 us; speedup 1.0000x reference)
//
#include <hip/hip_runtime.h>

typedef unsigned short u16;
typedef unsigned int u32;
typedef short bf16x8 __attribute__((ext_vector_type(8)));
typedef float f32x4 __attribute__((ext_vector_type(4)));

__device__ __forceinline__ u16 f2b(float f) {
    union { float f; unsigned u; } x; x.f = f;
    unsigned r = x.u + 0x7fffu + ((x.u >> 16) & 1u);
    return (u16)(r >> 16);
}

// ---------------------------------------------------------------- prep kernels

__global__ void conv_adj(const float* __restrict__ adj, u16* __restrict__ adjB) {
    size_t i = ((size_t)blockIdx.x * 256 + threadIdx.x) * 4;
    if (i < 16777216u) {
        float4 v = *(const float4*)(adj + i);
        u16* o = adjB + i;
        o[0] = f2b(v.x); o[1] = f2b(v.y); o[2] = f2b(v.z); o[3] = f2b(v.w);
    }
}

__global__ void prep_weights(const float* __restrict__ gw0, const float* __restrict__ gw1,
                             const float* __restrict__ gw2, const float* __restrict__ gw3,
                             u16* __restrict__ gw0T, u16* __restrict__ gw1T,
                             u16* __restrict__ gw2T, u16* __restrict__ gw3T) {
    int i = blockIdx.x * 256 + threadIdx.x;
    if (i < 128 * 320) {                 // gw0T [128][320], K pad 300->320
        int n = i / 320, k = i % 320;
        gw0T[i] = (k < 300) ? f2b(gw0[k * 128 + n]) : (u16)0;
    }
    if (i < 128 * 128) {                 // [128][128]
        int n = i >> 7, k = i & 127;
        gw1T[i] = f2b(gw1[k * 128 + n]);
        gw2T[i] = f2b(gw2[k * 128 + n]);
        gw3T[i] = (n < 50) ? f2b(gw3[k * 50 + n]) : (u16)0;   // N pad 50->128
    }
}

// ---------------------------------------------------------------- action MLP

__global__ void action_mlp(const float* __restrict__ mask,
                           const float* __restrict__ aw1, const float* __restrict__ ab1,
                           const float* __restrict__ aw2, const float* __restrict__ ab2,
                           const float* __restrict__ aw3, const float* __restrict__ ab3,
                           u16* __restrict__ aEmbB) {
    __shared__ float sm[50], sh1[200], sh2[100];
    int b = blockIdx.x, t = threadIdx.x;
    if (t < 50) sm[t] = mask[b * 50 + t];
    __syncthreads();
    if (t < 200) {
        float s = ab1[t];
        for (int k = 0; k < 50; ++k) s = fmaf(sm[k], aw1[k * 200 + t], s);
        sh1[t] = fmaxf(s, 0.f);
    }
    __syncthreads();
    if (t < 100) {
        float s = ab2[t];
        for (int k = 0; k < 200; ++k) s = fmaf(sh1[k], aw2[k * 100 + t], s);
        sh2[t] = fmaxf(s, 0.f);
    }
    __syncthreads();
    if (t < 100) {
        float s = ab3[t];
        for (int k = 0; k < 100; ++k) s = fmaf(sh2[k], aw3[k * 100 + t], s);
        aEmbB[b * 100 + t] = f2b(s);
    }
}

// ------------------------------------------------- node features (nerf + pos MLP + concat)
// 4 threads per node (wave w = final-layer channel slice w*25..w*25+24).
// Two-phase LDS staging (32 nodes per pass, 21.1 KB) for higher occupancy.

__global__ __launch_bounds__(256, 5)
void node_features(const float* __restrict__ mesh, const int* __restrict__ midx,
                   const float* __restrict__ emb,
                   const float* __restrict__ pw1, const float* __restrict__ pb1,
                   const float* __restrict__ pw2, const float* __restrict__ pb2,
                   const float* __restrict__ pw3, const float* __restrict__ pb3,
                   const u16* __restrict__ aEmbB, u16* __restrict__ X0) {
    __shared__ u16 st[32 * 330];          // 21120 B
    const int tid = threadIdx.x;
    const int w = tid >> 6;               // wave = channel slice 0..3
    const int n = tid & 63;               // node within block
    const size_t r = (size_t)blockIdx.x * 64 + n;
    const int bb = blockIdx.x >> 6;       // batch

    float m3[3];
    m3[0] = mesh[3 * r]; m3[1] = mesh[3 * r + 1]; m3[2] = mesh[3 * r + 2];

    float h1[25];
#pragma unroll
    for (int j = 0; j < 25; ++j) h1[j] = pb1[j];
#pragma unroll
    for (int d = 0; d < 3; ++d) {
#pragma unroll
        for (int i = 0; i < 10; ++i) {
            float fq = (i == 0) ? 3.14159265358979f : 6.28318530717959f * (float)i;
            float s, c;
            __sincosf(m3[d] * fq, &s, &c);
            int ks = i * 6 + d, kc = i * 6 + 3 + d;
#pragma unroll
            for (int j = 0; j < 25; ++j) h1[j] = fmaf(s, pw1[ks * 25 + j], h1[j]);
#pragma unroll
            for (int j = 0; j < 25; ++j) h1[j] = fmaf(c, pw1[kc * 25 + j], h1[j]);
        }
#pragma unroll
        for (int j = 0; j < 25; ++j) h1[j] = fmaf(m3[d], pw1[(60 + d) * 25 + j], h1[j]);
    }
#pragma unroll
    for (int j = 0; j < 25; ++j) h1[j] = fmaxf(h1[j], 0.f);

    float h2[50];
#pragma unroll
    for (int j = 0; j < 50; ++j) h2[j] = pb2[j];
#pragma unroll
    for (int k = 0; k < 25; ++k) {
        float x = h1[k];
#pragma unroll
        for (int j = 0; j < 50; ++j) h2[j] = fmaf(x, pw2[k * 50 + j], h2[j]);
    }
#pragma unroll
    for (int j = 0; j < 50; ++j) h2[j] = fmaxf(h2[j], 0.f);

    float pc[25];
#pragma unroll
    for (int j = 0; j < 25; ++j) pc[j] = pb3[w * 25 + j];
#pragma unroll
    for (int k = 0; k < 50; ++k) {
        float x = h2[k];
#pragma unroll
        for (int j = 0; j < 25; ++j) pc[j] = fmaf(x, pw3[k * 100 + w * 25 + j], pc[j]);
    }

    const int mi = midx[r];
    const float* erow = emb + mi * 100;

#pragma unroll
    for (int p = 0; p < 2; ++p) {
        if (p) __syncthreads();           // protect buffer reuse across phases
        if ((n >> 5) == p) {
            u16* row = st + (n & 31) * 330;
#pragma unroll
            for (int j = 0; j < 25; ++j) row[w * 25 + j] = aEmbB[bb * 100 + w * 25 + j];
#pragma unroll
            for (int j = 0; j < 25; ++j) row[100 + w * 25 + j] = f2b(pc[j]);
#pragma unroll
            for (int j = 0; j < 25; ++j) row[200 + w * 25 + j] = f2b(erow[w * 25 + j]);
#pragma unroll
            for (int j = 0; j < 5; ++j)  row[300 + w * 5 + j] = 0;
        }
        __syncthreads();
        u32* gout = (u32*)X0 + (size_t)blockIdx.x * 64 * 160 + (size_t)p * 32 * 160;
#pragma unroll
        for (int it = 0; it < 20; ++it) {
            int f = tid + it * 256;       // dword index 0..5119
            int rr = f / 160, cc = f - rr * 160;
            gout[f] = *(const u32*)((const char*)st + rr * 660 + cc * 4);
        }
    }
}

// ---------------------------------------------------------------- MFMA GEMM (C = A * B^T)
// A [M x kd] bf16 row-major, B [N x kd] bf16 row-major.
// 128x128 tile, 4 waves 2x2, 16x16x32 frags. Double-buffered LDS, ONE barrier
// per k-step: stage(next) issued before ds_read+MFMA(cur); __syncthreads'
// auto vmcnt/lgkm drain completes the handoff.
// LDS 16B-slot XOR swizzle (both-sides): BK=32: p = slot ^ ((row>>1)&3);
// BK=64: p = slot ^ (row&7). Staging pre-swizzles the GLOBAL source,
// LDS dest stays linear (global_load_lds constraint).
// EPI 0: feature GEMM layers 0-2 -> FT (c<42, transposed) + Xnext (relu, c>=42)
// EPI 1: feature GEMM layer 3    -> FT (c<50, transposed)
// EPI 2: adj GEMM layers 0-2     -> Xnext = relu(v + bias[l]), c = b*42+l < 672
// EPI 3: adj GEMM layer 3        -> AGG f32 = v + bias[l],     c = b*50+l < 800
template <int EPI, int BK>
__launch_bounds__(256)
__global__ void gemm_bt(const u16* __restrict__ A, const u16* __restrict__ B, int kd,
                        u16* __restrict__ outX, u16* __restrict__ outFT,
                        float* __restrict__ outF32, const float* __restrict__ bias) {
    __shared__ u16 As[2 * 128 * BK];
    __shared__ u16 Bs[2 * 128 * BK];
    constexpr int TB = 128 * BK * 2;      // tile bytes per buffer
    const int tid = threadIdx.x;
    const int wave = tid >> 6, lane = tid & 63;
    const int wr = wave >> 1, wc = wave & 1;
    const int tM = blockIdx.x * 128, tN = blockIdx.y * 128;
    const int lrow = lane & 15, kg = lane >> 4;

    // staging geometry (pre-swizzled global source, linear LDS dest)
    int srow, gcol;
    if (BK == 32) { srow = tid >> 2; gcol = ((tid & 3) ^ ((tid >> 3) & 3)) << 3; }
    else          { srow = tid >> 3; gcol = ((tid & 7) ^ ((tid >> 3) & 7)) << 3; }

    auto stage = [&](int buf, int kt) {
#pragma unroll
        for (int i = 0; i < BK / 16; ++i) {
            int row = (BK == 32) ? (i * 64 + srow) : (i * 32 + srow);
            const u16* ga = A + (size_t)(tM + row) * kd + kt + gcol;
            const u16* gb = B + (size_t)(tN + row) * kd + kt + gcol;
            int lbase = buf * TB + i * 4096 + wave * 1024;
            __builtin_amdgcn_global_load_lds(
                (__attribute__((address_space(1))) void*)ga,
                (__attribute__((address_space(3))) void*)((char*)(&As[0]) + lbase), 16, 0, 0);
            __builtin_amdgcn_global_load_lds(
                (__attribute__((address_space(1))) void*)gb,
                (__attribute__((address_space(3))) void*)((char*)(&Bs[0]) + lbase), 16, 0, 0);
        }
    };

    f32x4 acc[4][4];
#pragma unroll
    for (int m = 0; m < 4; ++m)
#pragma unroll
        for (int n = 0; n < 4; ++n) acc[m][n] = (f32x4){0.f, 0.f, 0.f, 0.f};

    const int nt = kd / BK;
    stage(0, 0);
    __syncthreads();                      // drain of prologue stage
    int cur = 0;
    for (int t = 0; t < nt; ++t) {
        if (t + 1 < nt) stage(cur ^ 1, (t + 1) * BK);
        if (BK == 32) {
            const int psw = (kg ^ ((lrow >> 1) & 3)) << 4;
            bf16x8 af[4], bfr[4];
#pragma unroll
            for (int m = 0; m < 4; ++m)
                af[m] = *(const bf16x8*)((const char*)As + cur * TB +
                                         (wr * 64 + m * 16 + lrow) * 64 + psw);
#pragma unroll
            for (int n = 0; n < 4; ++n)
                bfr[n] = *(const bf16x8*)((const char*)Bs + cur * TB +
                                          (wc * 64 + n * 16 + lrow) * 64 + psw);
#pragma unroll
            for (int m = 0; m < 4; ++m)
#pragma unroll
                for (int n = 0; n < 4; ++n)
                    acc[m][n] = __builtin_amdgcn_mfma_f32_16x16x32_bf16(af[m], bfr[n],
                                                                        acc[m][n], 0, 0, 0);
        } else {
            bf16x8 af[2][4], bfr[2][4];
#pragma unroll
            for (int ks = 0; ks < 2; ++ks) {
#pragma unroll
                for (int m = 0; m < 4; ++m) {
                    int row = wr * 64 + m * 16 + lrow;
                    int psw = (((ks * 4 + kg) ^ (row & 7)) << 4);
                    af[ks][m] = *(const bf16x8*)((const char*)As + cur * TB + row * 128 + psw);
                }
#pragma unroll
                for (int n = 0; n < 4; ++n) {
                    int row = wc * 64 + n * 16 + lrow;
                    int psw = (((ks * 4 + kg) ^ (row & 7)) << 4);
                    bfr[ks][n] = *(const bf16x8*)((const char*)Bs + cur * TB + row * 128 + psw);
                }
            }
#pragma unroll
            for (int ks = 0; ks < 2; ++ks)
#pragma unroll
                for (int m = 0; m < 4; ++m)
#pragma unroll
                    for (int n = 0; n < 4; ++n)
                        acc[m][n] = __builtin_amdgcn_mfma_f32_16x16x32_bf16(af[ks][m], bfr[ks][n],
                                                                            acc[m][n], 0, 0, 0);
        }
        __syncthreads();                  // drains staged vmcnt + lgkm; buffer handoff
        cur ^= 1;
    }

    const int rbase = tM + wr * 64 + ((lane >> 4) << 2);
    const int cbase = tN + wc * 64 + (lane & 15);
#pragma unroll
    for (int m = 0; m < 4; ++m) {
        int r0 = rbase + m * 16;                  // 4-aligned; j rows are r0..r0+3
#pragma unroll
        for (int n = 0; n < 4; ++n) {
            int c = cbase + n * 16;
            if (EPI == 0) {
                if (c < 42) {
                    int b = r0 >> 12, node = r0 & 4095;
                    u32 lo = (u32)f2b(acc[m][n][0]) | ((u32)f2b(acc[m][n][1]) << 16);
                    u32 hi = (u32)f2b(acc[m][n][2]) | ((u32)f2b(acc[m][n][3]) << 16);
                    u32* dst = (u32*)(outFT + (size_t)(b * 42 + c) * 4096 + node);
                    dst[0] = lo; dst[1] = hi;
                } else {
#pragma unroll
                    for (int j = 0; j < 4; ++j)
                        outX[(size_t)(r0 + j) * 128 + c] = f2b(fmaxf(acc[m][n][j], 0.f));
                }
            } else if (EPI == 1) {
                if (c < 50) {
                    int b = r0 >> 12, node = r0 & 4095;
                    u32 lo = (u32)f2b(acc[m][n][0]) | ((u32)f2b(acc[m][n][1]) << 16);
                    u32 hi = (u32)f2b(acc[m][n][2]) | ((u32)f2b(acc[m][n][3]) << 16);
                    u32* dst = (u32*)(outFT + (size_t)(b * 50 + c) * 4096 + node);
                    dst[0] = lo; dst[1] = hi;
                }
            } else if (EPI == 2) {
                if (c < 672) {
                    int b = c / 42, l = c - b * 42;
                    float bl = bias[l];
#pragma unroll
                    for (int j = 0; j < 4; ++j)
                        outX[(size_t)((b << 12) + r0 + j) * 128 + l] =
                            f2b(fmaxf(acc[m][n][j] + bl, 0.f));
                }
            } else {
                if (c < 800) {
                    int l = c % 50;
                    float bl = bias[l];
                    float4 v4 = {acc[m][n][0] + bl, acc[m][n][1] + bl,
                                 acc[m][n][2] + bl, acc[m][n][3] + bl};
                    *(float4*)(outF32 + (size_t)c * 4096 + r0) = v4;
                }
            }
        }
    }
}

// ---------------------------------------------------------------- final max over nodes

__global__ void max_reduce(const float* __restrict__ AGG, float* __restrict__ out) {
    __shared__ float sred[256];
    int c = blockIdx.x;                       // 0..799 == b*50+l
    const float* row = AGG + (size_t)c * 4096;
    float m = -1e30f;
    for (int i = threadIdx.x; i < 4096; i += 256) m = fmaxf(m, row[i]);
    sred[threadIdx.x] = m;
    __syncthreads();
    for (int s = 128; s > 0; s >>= 1) {
        if (threadIdx.x < s) sred[threadIdx.x] = fmaxf(sred[threadIdx.x], sred[threadIdx.x + s]);
        __syncthreads();
    }
    if (threadIdx.x == 0) out[c] = sred[0];
}

// ---------------------------------------------------------------- launch

extern "C" void kernel_launch(void* const* d_in, const int* in_sizes, int n_in,
                              void* d_out, int out_size, void* d_ws, size_t ws_size,
                              hipStream_t stream) {
    const float* mask = (const float*)d_in[0];
    const float* mesh = (const float*)d_in[1];
    const int*   midx = (const int*)d_in[2];
    const float* adj  = (const float*)d_in[3];
    const float* aw1 = (const float*)d_in[4],  *ab1 = (const float*)d_in[5];
    const float* aw2 = (const float*)d_in[6],  *ab2 = (const float*)d_in[7];
    const float* aw3 = (const float*)d_in[8],  *ab3 = (const float*)d_in[9];
    const float* pw1 = (const float*)d_in[10], *pb1 = (const float*)d_in[11];
    const float* pw2 = (const float*)d_in[12], *pb2 = (const float*)d_in[13];
    const float* pw3 = (const float*)d_in[14], *pb3 = (const float*)d_in[15];
    const float* emb = (const float*)d_in[16];
    const float* gw0 = (const float*)d_in[17], *gb0 = (const float*)d_in[18];
    const float* gw1 = (const float*)d_in[19], *gb1 = (const float*)d_in[20];
    const float* gw2 = (const float*)d_in[21], *gb2 = (const float*)d_in[22];
    const float* gw3 = (const float*)d_in[23], *gb3 = (const float*)d_in[24];
    float* out = (float*)d_out;

    char* w = (char*)d_ws;
    u16*   adjB  = (u16*)(w);                    // 33,554,432
    u16*   X0    = (u16*)(w + 33554432);         // 41,943,040
    float* AGG3  = (float*)(w + 33554432);       // overlay on X0 (dead by layer 3)
    u16*   X1    = (u16*)(w + 75497472);         // 16,777,216
    u16*   X2    = (u16*)(w + 92274688);         // 16,777,216
    u16*   FT    = (u16*)(w + 109051904);        // 896*4096*2 = 7,340,032
    u16*   gw0T  = (u16*)(w + 116391936);
    u16*   gw1T  = (u16*)(w + 116473856);
    u16*   gw2T  = (u16*)(w + 116506624);
    u16*   gw3T  = (u16*)(w + 116539392);
    u16*   aEmbB = (u16*)(w + 116572160);

    // zero FT pad rows (672..895) so padded GEMM columns read zeros
    hipMemsetAsync(FT + (size_t)672 * 4096, 0, (size_t)(896 - 672) * 4096 * 2, stream);

    prep_weights<<<dim3(160), dim3(256), 0, stream>>>(gw0, gw1, gw2, gw3, gw0T, gw1T, gw2T, gw3T);
    conv_adj<<<dim3(16384), dim3(256), 0, stream>>>(adj, adjB);
    action_mlp<<<dim3(16), dim3(256), 0, stream>>>(mask, aw1, ab1, aw2, ab2, aw3, ab3, aEmbB);
    node_features<<<dim3(1024), dim3(256), 0, stream>>>(mesh, midx, emb, pw1, pb1, pw2, pb2,
                                                        pw3, pb3, aEmbB, X0);
    // layer 0
    gemm_bt<0, 32><<<dim3(512, 1), dim3(256), 0, stream>>>(X0, gw0T, 320, X1, FT, nullptr, nullptr);
    gemm_bt<2, 64><<<dim3(32, 6), dim3(256), 0, stream>>>(adjB, FT, 4096, X1, nullptr, nullptr, gb0);
    // layer 1
    gemm_bt<0, 32><<<dim3(512, 1), dim3(256), 0, stream>>>(X1, gw1T, 128, X2, FT, nullptr, nullptr);
    gemm_bt<2, 64><<<dim3(32, 6), dim3(256), 0, stream>>>(adjB, FT, 4096, X2, nullptr, nullptr, gb1);
    // layer 2
    gemm_bt<0, 32><<<dim3(512, 1), dim3(256), 0, stream>>>(X2, gw2T, 128, X1, FT, nullptr, nullptr);
    gemm_bt<2, 64><<<dim3(32, 6), dim3(256), 0, stream>>>(adjB, FT, 4096, X1, nullptr, nullptr, gb2);
    // layer 3
    gemm_bt<1, 32><<<dim3(512, 1), dim3(256), 0, stream>>>(X1, gw3T, 128, nullptr, FT, nullptr, nullptr);
    gemm_bt<3, 64><<<dim3(32, 7), dim3(256), 0, stream>>>(adjB, FT, 4096, nullptr, nullptr, AGG3, gb3);

    max_reduce<<<dim3(800), dim3(256), 0, stream>>>(AGG3, out);
}

// Round 6
// 558.103 us; speedup vs baseline: 1.5769x; 1.5769x over previous
//
#include <hip/hip_runtime.h>

typedef unsigned short u16;
typedef unsigned int u32;
typedef short bf16x8 __attribute__((ext_vector_type(8)));
typedef float f32x4 __attribute__((ext_vector_type(4)));

__device__ __forceinline__ u16 f2b(float f) {
    union { float f; unsigned u; } x; x.f = f;
    unsigned r = x.u + 0x7fffu + ((x.u >> 16) & 1u);
    return (u16)(r >> 16);
}

// ---------------------------------------------------------------- prep kernels

__global__ void conv_adj(const float* __restrict__ adj, u16* __restrict__ adjB) {
    size_t i = ((size_t)blockIdx.x * 256 + threadIdx.x) * 4;
    if (i < 16777216u) {
        float4 v = *(const float4*)(adj + i);
        u16* o = adjB + i;
        o[0] = f2b(v.x); o[1] = f2b(v.y); o[2] = f2b(v.z); o[3] = f2b(v.w);
    }
}

__global__ void prep_weights(const float* __restrict__ gw0, const float* __restrict__ gw1,
                             const float* __restrict__ gw2, const float* __restrict__ gw3,
                             u16* __restrict__ gw0T, u16* __restrict__ gw1T,
                             u16* __restrict__ gw2T, u16* __restrict__ gw3T) {
    int i = blockIdx.x * 256 + threadIdx.x;
    if (i < 128 * 320) {                 // gw0T [128][320], K pad 300->320
        int n = i / 320, k = i % 320;
        gw0T[i] = (k < 300) ? f2b(gw0[k * 128 + n]) : (u16)0;
    }
    if (i < 128 * 128) {                 // [128][128]
        int n = i >> 7, k = i & 127;
        gw1T[i] = f2b(gw1[k * 128 + n]);
        gw2T[i] = f2b(gw2[k * 128 + n]);
        gw3T[i] = (n < 50) ? f2b(gw3[k * 50 + n]) : (u16)0;   // N pad 50->128
    }
}

// ---------------------------------------------------------------- action MLP

__global__ void action_mlp(const float* __restrict__ mask,
                           const float* __restrict__ aw1, const float* __restrict__ ab1,
                           const float* __restrict__ aw2, const float* __restrict__ ab2,
                           const float* __restrict__ aw3, const float* __restrict__ ab3,
                           u16* __restrict__ aEmbB) {
    __shared__ float sm[50], sh1[200], sh2[100];
    int b = blockIdx.x, t = threadIdx.x;
    if (t < 50) sm[t] = mask[b * 50 + t];
    __syncthreads();
    if (t < 200) {
        float s = ab1[t];
        for (int k = 0; k < 50; ++k) s = fmaf(sm[k], aw1[k * 200 + t], s);
        sh1[t] = fmaxf(s, 0.f);
    }
    __syncthreads();
    if (t < 100) {
        float s = ab2[t];
        for (int k = 0; k < 200; ++k) s = fmaf(sh1[k], aw2[k * 100 + t], s);
        sh2[t] = fmaxf(s, 0.f);
    }
    __syncthreads();
    if (t < 100) {
        float s = ab3[t];
        for (int k = 0; k < 100; ++k) s = fmaf(sh2[k], aw3[k * 100 + t], s);
        aEmbB[b * 100 + t] = f2b(s);
    }
}

// ------------------------------------------------- node features (nerf + pos MLP + concat)
// 4 threads per node. Two-phase LDS staging (21.1 KB). NO min-waves clause:
// launch_bounds(256,5) in R5 forced VGPR 120->48 and spilled h1/h2/pc to
// scratch (600 MB of scratch traffic, 113us -> 345us).

__global__ __launch_bounds__(256)
void node_features(const float* __restrict__ mesh, const int* __restrict__ midx,
                   const float* __restrict__ emb,
                   const float* __restrict__ pw1, const float* __restrict__ pb1,
                   const float* __restrict__ pw2, const float* __restrict__ pb2,
                   const float* __restrict__ pw3, const float* __restrict__ pb3,
                   const u16* __restrict__ aEmbB, u16* __restrict__ X0) {
    __shared__ u16 st[32 * 330];          // 21120 B
    const int tid = threadIdx.x;
    const int w = tid >> 6;               // wave = channel slice 0..3
    const int n = tid & 63;               // node within block
    const size_t r = (size_t)blockIdx.x * 64 + n;
    const int bb = blockIdx.x >> 6;       // batch

    float m3[3];
    m3[0] = mesh[3 * r]; m3[1] = mesh[3 * r + 1]; m3[2] = mesh[3 * r + 2];

    float h1[25];
#pragma unroll
    for (int j = 0; j < 25; ++j) h1[j] = pb1[j];
#pragma unroll
    for (int d = 0; d < 3; ++d) {
#pragma unroll
        for (int i = 0; i < 10; ++i) {
            float fq = (i == 0) ? 3.14159265358979f : 6.28318530717959f * (float)i;
            float s, c;
            __sincosf(m3[d] * fq, &s, &c);
            int ks = i * 6 + d, kc = i * 6 + 3 + d;
#pragma unroll
            for (int j = 0; j < 25; ++j) h1[j] = fmaf(s, pw1[ks * 25 + j], h1[j]);
#pragma unroll
            for (int j = 0; j < 25; ++j) h1[j] = fmaf(c, pw1[kc * 25 + j], h1[j]);
        }
#pragma unroll
        for (int j = 0; j < 25; ++j) h1[j] = fmaf(m3[d], pw1[(60 + d) * 25 + j], h1[j]);
    }
#pragma unroll
    for (int j = 0; j < 25; ++j) h1[j] = fmaxf(h1[j], 0.f);

    float h2[50];
#pragma unroll
    for (int j = 0; j < 50; ++j) h2[j] = pb2[j];
#pragma unroll
    for (int k = 0; k < 25; ++k) {
        float x = h1[k];
#pragma unroll
        for (int j = 0; j < 50; ++j) h2[j] = fmaf(x, pw2[k * 50 + j], h2[j]);
    }
#pragma unroll
    for (int j = 0; j < 50; ++j) h2[j] = fmaxf(h2[j], 0.f);

    float pc[25];
#pragma unroll
    for (int j = 0; j < 25; ++j) pc[j] = pb3[w * 25 + j];
#pragma unroll
    for (int k = 0; k < 50; ++k) {
        float x = h2[k];
#pragma unroll
        for (int j = 0; j < 25; ++j) pc[j] = fmaf(x, pw3[k * 100 + w * 25 + j], pc[j]);
    }

    const int mi = midx[r];
    const float* erow = emb + mi * 100;

#pragma unroll
    for (int p = 0; p < 2; ++p) {
        if (p) __syncthreads();           // protect buffer reuse across phases
        if ((n >> 5) == p) {
            u16* row = st + (n & 31) * 330;
#pragma unroll
            for (int j = 0; j < 25; ++j) row[w * 25 + j] = aEmbB[bb * 100 + w * 25 + j];
#pragma unroll
            for (int j = 0; j < 25; ++j) row[100 + w * 25 + j] = f2b(pc[j]);
#pragma unroll
            for (int j = 0; j < 25; ++j) row[200 + w * 25 + j] = f2b(erow[w * 25 + j]);
#pragma unroll
            for (int j = 0; j < 5; ++j)  row[300 + w * 5 + j] = 0;
        }
        __syncthreads();
        u32* gout = (u32*)X0 + (size_t)blockIdx.x * 64 * 160 + (size_t)p * 32 * 160;
#pragma unroll
        for (int it = 0; it < 20; ++it) {
            int f = tid + it * 256;       // dword index 0..5119
            int rr = f / 160, cc = f - rr * 160;
            gout[f] = *(const u32*)((const char*)st + rr * 660 + cc * 4);
        }
    }
}

// ---------------------------------------------------------------- MFMA GEMM (C = A * B^T)
// A [M x kd] bf16 row-major (M tile 128), B [N x kd] bf16 row-major (N tile BN).
// BK=64, double-buffered LDS, COUNTED-vmcnt pipeline (T3/T4): raw s_barrier,
// never __syncthreads (its vmcnt(0) drains the prefetch - R5 lesson). Per step:
//   waitcnt vmcnt(NLOADS)  <- tile-t loads done, tile-t+1 loads stay in flight
//   s_barrier; sched_barrier(0)
//   ds_read + MFMA (setprio 1)
//   s_barrier                <- all waves consumed buf -> safe to overwrite
//   stage(t+2) into just-consumed buffer
// LDS 16B-slot XOR swizzle: phys slot = logical ^ (row&7); staging pre-swizzles
// the GLOBAL source (linear LDS dest, global_load_lds constraint).
// EPI 0: feature GEMM layers 0-2 -> FT (c<42, transposed) + Xnext (relu, c>=42)
// EPI 1: feature GEMM layer 3    -> FT (c<50, transposed)
// EPI 2: adj GEMM layers 0-2     -> Xnext = relu(v + bias[l]), c = b*42+l < 672
// EPI 3: adj GEMM layer 3        -> AGG f32 = v + bias[l],     c = b*50+l < 800
template <int EPI, int BN>
__launch_bounds__(256)
__global__ void gemm_bt(const u16* __restrict__ A, const u16* __restrict__ B, int kd,
                        u16* __restrict__ outX, u16* __restrict__ outFT,
                        float* __restrict__ outF32, const float* __restrict__ bias) {
    constexpr int NF = BN / 32;           // n-frags per wave (4 or 3)
    constexpr int BPASS = BN / 32;        // B staging passes (32 rows each)
    __shared__ u16 As[2 * 128 * 64];
    __shared__ u16 Bs[2 * BN * 64];
    constexpr int TBA = 128 * 64 * 2;     // bytes per A buffer
    constexpr int TBB = BN * 64 * 2;
    const int tid = threadIdx.x;
    const int wave = tid >> 6, lane = tid & 63;
    const int wr = wave >> 1, wc = wave & 1;
    const int tM = blockIdx.x * 128, tN = blockIdx.y * BN;
    const int lrow = lane & 15, kg = lane >> 4;
    const int srow = tid >> 3;            // 32 rows per staging pass
    const int gcol = ((tid & 7) ^ ((tid >> 3) & 7)) << 3;   // pre-swizzled col (elems)

    auto stage = [&](int buf, int kt) {
#pragma unroll
        for (int i = 0; i < 4; ++i) {     // A: 128 rows
            int row = i * 32 + srow;
            const u16* ga = A + (size_t)(tM + row) * kd + kt + gcol;
            __builtin_amdgcn_global_load_lds(
                (__attribute__((address_space(1))) void*)ga,
                (__attribute__((address_space(3))) void*)((char*)(&As[0]) +
                    buf * TBA + i * 4096 + wave * 1024), 16, 0, 0);
        }
#pragma unroll
        for (int i = 0; i < BPASS; ++i) { // B: BN rows
            int row = i * 32 + srow;
            const u16* gb = B + (size_t)(tN + row) * kd + kt + gcol;
            __builtin_amdgcn_global_load_lds(
                (__attribute__((address_space(1))) void*)gb,
                (__attribute__((address_space(3))) void*)((char*)(&Bs[0]) +
                    buf * TBB + i * 4096 + wave * 1024), 16, 0, 0);
        }
    };

    f32x4 acc[4][NF];
#pragma unroll
    for (int m = 0; m < 4; ++m)
#pragma unroll
        for (int n = 0; n < NF; ++n) acc[m][n] = (f32x4){0.f, 0.f, 0.f, 0.f};

    const int nt = kd >> 6;               // kd in {128, 320, 4096}: nt >= 2
    stage(0, 0);
    stage(1, 64);
    for (int t = 0; t < nt; ++t) {
        if (t == nt - 1)              asm volatile("s_waitcnt vmcnt(0)" ::: "memory");
        else if constexpr (BN == 128) asm volatile("s_waitcnt vmcnt(8)" ::: "memory");
        else                          asm volatile("s_waitcnt vmcnt(7)" ::: "memory");
        __builtin_amdgcn_s_barrier();
        __builtin_amdgcn_sched_barrier(0);

        const char* Ab = (const char*)As + (t & 1) * TBA;
        const char* Bb = (const char*)Bs + (t & 1) * TBB;
        bf16x8 af[2][4], bfr[2][NF];
#pragma unroll
        for (int ks = 0; ks < 2; ++ks) {
#pragma unroll
            for (int m = 0; m < 4; ++m) {
                int row = wr * 64 + m * 16 + lrow;
                int psw = (((ks * 4 + kg) ^ (row & 7)) << 4);
                af[ks][m] = *(const bf16x8*)(Ab + row * 128 + psw);
            }
#pragma unroll
            for (int n = 0; n < NF; ++n) {
                int row = wc * (BN / 2) + n * 16 + lrow;
                int psw = (((ks * 4 + kg) ^ (row & 7)) << 4);
                bfr[ks][n] = *(const bf16x8*)(Bb + row * 128 + psw);
            }
        }
        __builtin_amdgcn_s_setprio(1);
#pragma unroll
        for (int ks = 0; ks < 2; ++ks)
#pragma unroll
            for (int m = 0; m < 4; ++m)
#pragma unroll
                for (int n = 0; n < NF; ++n)
                    acc[m][n] = __builtin_amdgcn_mfma_f32_16x16x32_bf16(af[ks][m], bfr[ks][n],
                                                                        acc[m][n], 0, 0, 0);
        __builtin_amdgcn_s_setprio(0);
        __builtin_amdgcn_s_barrier();     // all waves consumed buf (t&1)
        if (t + 2 < nt) stage(t & 1, (t + 2) * 64);
    }

    const int rbase = tM + wr * 64 + ((lane >> 4) << 2);
    const int cbase = tN + wc * (BN / 2) + (lane & 15);
#pragma unroll
    for (int m = 0; m < 4; ++m) {
        int r0 = rbase + m * 16;                  // 4-aligned; j rows are r0..r0+3
#pragma unroll
        for (int n = 0; n < NF; ++n) {
            int c = cbase + n * 16;
            if (EPI == 0) {
                if (c < 42) {
                    int b = r0 >> 12, node = r0 & 4095;
                    u32 lo = (u32)f2b(acc[m][n][0]) | ((u32)f2b(acc[m][n][1]) << 16);
                    u32 hi = (u32)f2b(acc[m][n][2]) | ((u32)f2b(acc[m][n][3]) << 16);
                    u32* dst = (u32*)(outFT + (size_t)(b * 42 + c) * 4096 + node);
                    dst[0] = lo; dst[1] = hi;
                } else {
#pragma unroll
                    for (int j = 0; j < 4; ++j)
                        outX[(size_t)(r0 + j) * 128 + c] = f2b(fmaxf(acc[m][n][j], 0.f));
                }
            } else if (EPI == 1) {
                if (c < 50) {
                    int b = r0 >> 12, node = r0 & 4095;
                    u32 lo = (u32)f2b(acc[m][n][0]) | ((u32)f2b(acc[m][n][1]) << 16);
                    u32 hi = (u32)f2b(acc[m][n][2]) | ((u32)f2b(acc[m][n][3]) << 16);
                    u32* dst = (u32*)(outFT + (size_t)(b * 50 + c) * 4096 + node);
                    dst[0] = lo; dst[1] = hi;
                }
            } else if (EPI == 2) {
                if (c < 672) {
                    int b = c / 42, l = c - b * 42;
                    float bl = bias[l];
#pragma unroll
                    for (int j = 0; j < 4; ++j)
                        outX[(size_t)((b << 12) + r0 + j) * 128 + l] =
                            f2b(fmaxf(acc[m][n][j] + bl, 0.f));
                }
            } else {
                if (c < 800) {
                    int l = c % 50;
                    float bl = bias[l];
                    float4 v4 = {acc[m][n][0] + bl, acc[m][n][1] + bl,
                                 acc[m][n][2] + bl, acc[m][n][3] + bl};
                    *(float4*)(outF32 + (size_t)c * 4096 + r0) = v4;
                }
            }
        }
    }
}

// ---------------------------------------------------------------- final max over nodes

__global__ void max_reduce(const float* __restrict__ AGG, float* __restrict__ out) {
    __shared__ float sred[256];
    int c = blockIdx.x;                       // 0..799 == b*50+l
    const float* row = AGG + (size_t)c * 4096;
    float m = -1e30f;
    for (int i = threadIdx.x; i < 4096; i += 256) m = fmaxf(m, row[i]);
    sred[threadIdx.x] = m;
    __syncthreads();
    for (int s = 128; s > 0; s >>= 1) {
        if (threadIdx.x < s) sred[threadIdx.x] = fmaxf(sred[threadIdx.x], sred[threadIdx.x + s]);
        __syncthreads();
    }
    if (threadIdx.x == 0) out[c] = sred[0];
}

// ---------------------------------------------------------------- launch

extern "C" void kernel_launch(void* const* d_in, const int* in_sizes, int n_in,
                              void* d_out, int out_size, void* d_ws, size_t ws_size,
                              hipStream_t stream) {
    const float* mask = (const float*)d_in[0];
    const float* mesh = (const float*)d_in[1];
    const int*   midx = (const int*)d_in[2];
    const float* adj  = (const float*)d_in[3];
    const float* aw1 = (const float*)d_in[4],  *ab1 = (const float*)d_in[5];
    const float* aw2 = (const float*)d_in[6],  *ab2 = (const float*)d_in[7];
    const float* aw3 = (const float*)d_in[8],  *ab3 = (const float*)d_in[9];
    const float* pw1 = (const float*)d_in[10], *pb1 = (const float*)d_in[11];
    const float* pw2 = (const float*)d_in[12], *pb2 = (const float*)d_in[13];
    const float* pw3 = (const float*)d_in[14], *pb3 = (const float*)d_in[15];
    const float* emb = (const float*)d_in[16];
    const float* gw0 = (const float*)d_in[17], *gb0 = (const float*)d_in[18];
    const float* gw1 = (const float*)d_in[19], *gb1 = (const float*)d_in[20];
    const float* gw2 = (const float*)d_in[21], *gb2 = (const float*)d_in[22];
    const float* gw3 = (const float*)d_in[23], *gb3 = (const float*)d_in[24];
    float* out = (float*)d_out;

    char* w = (char*)d_ws;
    u16*   adjB  = (u16*)(w);                    // 33,554,432
    u16*   X0    = (u16*)(w + 33554432);         // 41,943,040
    float* AGG3  = (float*)(w + 33554432);       // overlay on X0 (dead by layer 3)
    u16*   X1    = (u16*)(w + 75497472);         // 16,777,216
    u16*   X2    = (u16*)(w + 92274688);         // 16,777,216
    u16*   FT    = (u16*)(w + 109051904);        // 896*4096*2 = 7,340,032
    u16*   gw0T  = (u16*)(w + 116391936);
    u16*   gw1T  = (u16*)(w + 116473856);
    u16*   gw2T  = (u16*)(w + 116506624);
    u16*   gw3T  = (u16*)(w + 116539392);
    u16*   aEmbB = (u16*)(w + 116572160);

    // zero FT pad rows (672..895): padded GEMM B-tiles read zeros
    hipMemsetAsync(FT + (size_t)672 * 4096, 0, (size_t)(896 - 672) * 4096 * 2, stream);

    prep_weights<<<dim3(160), dim3(256), 0, stream>>>(gw0, gw1, gw2, gw3, gw0T, gw1T, gw2T, gw3T);
    conv_adj<<<dim3(16384), dim3(256), 0, stream>>>(adj, adjB);
    action_mlp<<<dim3(16), dim3(256), 0, stream>>>(mask, aw1, ab1, aw2, ab2, aw3, ab3, aEmbB);
    node_features<<<dim3(1024), dim3(256), 0, stream>>>(mesh, midx, emb, pw1, pb1, pw2, pb2,
                                                        pw3, pb3, aEmbB, X0);
    // layer 0
    gemm_bt<0, 128><<<dim3(512, 1), dim3(256), 0, stream>>>(X0, gw0T, 320, X1, FT, nullptr, nullptr);
    gemm_bt<2, 96><<<dim3(32, 8), dim3(256), 0, stream>>>(adjB, FT, 4096, X1, nullptr, nullptr, gb0);
    // layer 1
    gemm_bt<0, 128><<<dim3(512, 1), dim3(256), 0, stream>>>(X1, gw1T, 128, X2, FT, nullptr, nullptr);
    gemm_bt<2, 96><<<dim3(32, 8), dim3(256), 0, stream>>>(adjB, FT, 4096, X2, nullptr, nullptr, gb1);
    // layer 2
    gemm_bt<0, 128><<<dim3(512, 1), dim3(256), 0, stream>>>(X2, gw2T, 128, X1, FT, nullptr, nullptr);
    gemm_bt<2, 96><<<dim3(32, 8), dim3(256), 0, stream>>>(adjB, FT, 4096, X1, nullptr, nullptr, gb2);
    // layer 3
    gemm_bt<1, 128><<<dim3(512, 1), dim3(256), 0, stream>>>(X1, gw3T, 128, nullptr, FT, nullptr, nullptr);
    gemm_bt<3, 96><<<dim3(32, 9), dim3(256), 0, stream>>>(adjB, FT, 4096, nullptr, nullptr, AGG3, gb3);

    max_reduce<<<dim3(800), dim3(256), 0, stream>>>(AGG3, out);
}

// Round 8
// 408.162 us; speedup vs baseline: 2.1562x; 1.3674x over previous
//
#include <hip/hip_runtime.h>

typedef unsigned short u16;
typedef unsigned int u32;
typedef short bf16x8 __attribute__((ext_vector_type(8)));
typedef float f32x4 __attribute__((ext_vector_type(4)));

__device__ __forceinline__ u16 f2b(float f) {
    union { float f; unsigned u; } x; x.f = f;
    unsigned r = x.u + 0x7fffu + ((x.u >> 16) & 1u);
    return (u16)(r >> 16);
}

// ---------------------------------------------------------------- prep kernels

__global__ void conv_adj(const float* __restrict__ adj, u16* __restrict__ adjB) {
    size_t i = ((size_t)blockIdx.x * 256 + threadIdx.x) * 4;
    if (i < 16777216u) {
        float4 v = *(const float4*)(adj + i);
        u16* o = adjB + i;
        o[0] = f2b(v.x); o[1] = f2b(v.y); o[2] = f2b(v.z); o[3] = f2b(v.w);
    }
}

__global__ void prep_weights(const float* __restrict__ gw1, const float* __restrict__ gw2,
                             const float* __restrict__ gw3,
                             u16* __restrict__ gw1T, u16* __restrict__ gw2T,
                             u16* __restrict__ gw3T) {
    int i = blockIdx.x * 256 + threadIdx.x;
    if (i < 128 * 128) {                 // [N=128][K=128]
        int n = i >> 7, k = i & 127;
        gw1T[i] = f2b(gw1[k * 128 + n]);
        gw2T[i] = f2b(gw2[k * 128 + n]);
        gw3T[i] = (n < 50) ? f2b(gw3[k * 50 + n]) : (u16)0;   // N pad 50->128
    }
}

// ---------------------------------------------------------------- action MLP (f32 out)

__global__ void action_mlp(const float* __restrict__ mask,
                           const float* __restrict__ aw1, const float* __restrict__ ab1,
                           const float* __restrict__ aw2, const float* __restrict__ ab2,
                           const float* __restrict__ aw3, const float* __restrict__ ab3,
                           float* __restrict__ aF) {
    __shared__ float sm[50], sh1[200], sh2[100];
    int b = blockIdx.x, t = threadIdx.x;
    if (t < 50) sm[t] = mask[b * 50 + t];
    __syncthreads();
    if (t < 200) {
        float s = ab1[t];
        for (int k = 0; k < 50; ++k) s = fmaf(sm[k], aw1[k * 200 + t], s);
        sh1[t] = fmaxf(s, 0.f);
    }
    __syncthreads();
    if (t < 100) {
        float s = ab2[t];
        for (int k = 0; k < 200; ++k) s = fmaf(sh1[k], aw2[k * 100 + t], s);
        sh2[t] = fmaxf(s, 0.f);
    }
    __syncthreads();
    if (t < 100) {
        float s = ab3[t];
        for (int k = 0; k < 100; ++k) s = fmaf(sh2[k], aw3[k * 100 + t], s);
        aF[b * 100 + t] = s;
    }
}

// ---------------------------------------------------------------- layer-0 fold precompute
// A2[b][n] = a[b]@gw0_top + pb3@gw0_mid      (f32, 16x128)
// Ep[e][n] = emb[e]@gw0_bot                  (f32, 4x128)
// WpT[n][k] = (pw3@gw0_mid)^T                (bf16, 128x64, k>=50 zero)

__global__ void prep_fold(const float* __restrict__ aF, const float* __restrict__ pb3,
                          const float* __restrict__ pw3, const float* __restrict__ emb,
                          const float* __restrict__ gw0,
                          float* __restrict__ A2, float* __restrict__ Ep,
                          u16* __restrict__ WpT) {
    int idx = blockIdx.x * 256 + threadIdx.x;
    if (idx < 2048) {
        int b = idx >> 7, n = idx & 127;
        float s = 0.f;
        for (int j = 0; j < 100; ++j) s = fmaf(aF[b * 100 + j], gw0[j * 128 + n], s);
        for (int j = 0; j < 100; ++j) s = fmaf(pb3[j], gw0[(100 + j) * 128 + n], s);
        A2[idx] = s;
    } else if (idx < 2560) {
        int e = (idx - 2048) >> 7, n = idx & 127;
        float s = 0.f;
        for (int j = 0; j < 100; ++j) s = fmaf(emb[e * 100 + j], gw0[(200 + j) * 128 + n], s);
        Ep[idx - 2048] = s;
    } else if (idx < 10752) {
        int o = idx - 2560;
        int n = o >> 6, k = o & 63;
        u16 v = 0;
        if (k < 50) {
            float s = 0.f;
            for (int c = 0; c < 100; ++c) s = fmaf(pw3[k * 100 + c], gw0[(100 + c) * 128 + n], s);
            v = f2b(s);
        }
        WpT[o] = v;
    }
}

// ------------------------------------------------- nf_h2r: nerf + pos-MLP layers 1-2
// 4 threads/node, per-layer channel split with LDS exchange (8% redundancy).
// Output H2R [65536][64] bf16 (cols 50..63 zero).

__global__ __launch_bounds__(256)
void nf_h2r(const float* __restrict__ mesh,
            const float* __restrict__ pw1, const float* __restrict__ pb1,
            const float* __restrict__ pw2, const float* __restrict__ pb2,
            u16* __restrict__ H2R) {
    __shared__ float h1x[64 * 29];        // 7424 B, stride 29 (odd) -> conflict-free
    __shared__ u16 st[64 * 66];           // 8448 B, dword stride 33 -> conflict-free
    const int tid = threadIdx.x;
    const int wu = __builtin_amdgcn_readfirstlane(tid >> 6);  // wave slice, uniform
    const int t = tid & 63;               // node within block
    const size_t r = (size_t)blockIdx.x * 64 + t;

    float m3[3];
    m3[0] = mesh[3 * r]; m3[1] = mesh[3 * r + 1]; m3[2] = mesh[3 * r + 2];

    // h1 slice: cols wu*7 .. wu*7+6 (clamped addressing; store only valid)
    int ec[7];
    float hs[7];
#pragma unroll
    for (int j = 0; j < 7; ++j) {
        int col = wu * 7 + j;
        ec[j] = (col < 25) ? col : 24;
        hs[j] = pb1[ec[j]];
    }
#pragma unroll
    for (int d = 0; d < 3; ++d) {
#pragma unroll
        for (int i = 0; i < 10; ++i) {
            float fq = (i == 0) ? 3.14159265358979f : 6.28318530717959f * (float)i;
            float s, c;
            __sincosf(m3[d] * fq, &s, &c);
            int ks = i * 6 + d, kc = i * 6 + 3 + d;
#pragma unroll
            for (int j = 0; j < 7; ++j) hs[j] = fmaf(s, pw1[ks * 25 + ec[j]], hs[j]);
#pragma unroll
            for (int j = 0; j < 7; ++j) hs[j] = fmaf(c, pw1[kc * 25 + ec[j]], hs[j]);
        }
#pragma unroll
        for (int j = 0; j < 7; ++j) hs[j] = fmaf(m3[d], pw1[(60 + d) * 25 + ec[j]], hs[j]);
    }
#pragma unroll
    for (int j = 0; j < 7; ++j) {
        int col = wu * 7 + j;
        if (col < 25) h1x[t * 29 + col] = fmaxf(hs[j], 0.f);
    }
    __syncthreads();

    float h1v[25];
#pragma unroll
    for (int k = 0; k < 25; ++k) h1v[k] = h1x[t * 29 + k];

    // h2 slice: cols wu*13 .. wu*13+12 (valid < 50), pack bf16 to LDS
#pragma unroll
    for (int j = 0; j < 13; ++j) {
        int col = wu * 13 + j;
        int e2 = (col < 50) ? col : 49;
        float s = pb2[e2];
#pragma unroll
        for (int k = 0; k < 25; ++k) s = fmaf(h1v[k], pw2[k * 50 + e2], s);
        st[t * 66 + col] = (col < 50) ? f2b(fmaxf(s, 0.f)) : (u16)0;
    }
    if (wu == 3) {
#pragma unroll
        for (int jj = 0; jj < 12; ++jj) st[t * 66 + 52 + jj] = 0;   // K pad 52..63
    }
    __syncthreads();

    // drain: 64 rows x 32 dwords, fully coalesced
    u32* gout = (u32*)H2R + (size_t)blockIdx.x * 2048;
#pragma unroll
    for (int it = 0; it < 8; ++it) {
        int f = tid + it * 256;
        int row = f >> 5, col = f & 31;
        gout[f] = *((const u32*)st + row * 33 + col);
    }
}

// ---------------------------------------------------------------- MFMA GEMM (C = A * B^T)
// A [M x kd] bf16 row-major (M tile 128), B [N x kd] bf16 row-major (N tile BN).
// BK=64, dbuf LDS, counted-vmcnt pipeline (R6 structure). kd = row stride,
// klen = K extent per block; blockIdx.z = K-split slice.
// EPI 0: feature GEMM layers 1-2 -> FT (c<42, transposed) + Xnext (relu, c>=42)
// EPI 1: feature GEMM layer 3    -> FT (c<50, transposed)
// EPI 4: layer-0 fold GEMM: v = acc + A2[b][c] + Ep[mi[r]][c] -> FT/X like EPI0
// EPI 6: adj GEMM split-K       -> f32 partial P[z][c][r], no bias
template <int EPI, int BN>
__launch_bounds__(256)
__global__ void gemm_bt(const u16* __restrict__ A, const u16* __restrict__ B,
                        int kd, int klen,
                        u16* __restrict__ outX, u16* __restrict__ outFT,
                        float* __restrict__ outF32,
                        const float* __restrict__ A2, const float* __restrict__ Ep,
                        const int* __restrict__ midx, int ncol) {
    constexpr int NF = BN / 32;           // n-frags per wave
    constexpr int BPASS = BN / 32;        // B staging passes (32 rows each)
    __shared__ u16 As[2 * 128 * 64];
    __shared__ u16 Bs[2 * BN * 64];
    __shared__ float aadd[128];
    __shared__ float eadd[512];
    __shared__ int mil[128];
    constexpr int TBA = 128 * 64 * 2;
    constexpr int TBB = BN * 64 * 2;
    const int tid = threadIdx.x;
    const int wave = tid >> 6, lane = tid & 63;
    const int wr = wave >> 1, wc = wave & 1;
    const int tM = blockIdx.x * 128, tN = blockIdx.y * BN;
    const int lrow = lane & 15, kg = lane >> 4;
    const int srow = tid >> 3;
    const int gcol = ((tid & 7) ^ ((tid >> 3) & 7)) << 3;
    const int k0 = blockIdx.z * klen;

    if constexpr (EPI == 4) {
        if (tid < 128) { mil[tid] = midx[tM + tid]; aadd[tid] = A2[((tM >> 12) << 7) + tid]; }
        // R7 BUG FIX: 512 entries, 256 threads -> each thread loads TWO
        eadd[tid] = Ep[tid];
        eadd[tid + 256] = Ep[tid + 256];
        __syncthreads();
    }

    auto stage = [&](int buf, int kt) {
#pragma unroll
        for (int i = 0; i < 4; ++i) {
            int row = i * 32 + srow;
            const u16* ga = A + (size_t)(tM + row) * kd + kt + gcol;
            __builtin_amdgcn_global_load_lds(
                (__attribute__((address_space(1))) void*)ga,
                (__attribute__((address_space(3))) void*)((char*)(&As[0]) +
                    buf * TBA + i * 4096 + wave * 1024), 16, 0, 0);
        }
#pragma unroll
        for (int i = 0; i < BPASS; ++i) {
            int row = i * 32 + srow;
            const u16* gb = B + (size_t)(tN + row) * kd + kt + gcol;
            __builtin_amdgcn_global_load_lds(
                (__attribute__((address_space(1))) void*)gb,
                (__attribute__((address_space(3))) void*)((char*)(&Bs[0]) +
                    buf * TBB + i * 4096 + wave * 1024), 16, 0, 0);
        }
    };

    f32x4 acc[4][NF];
#pragma unroll
    for (int m = 0; m < 4; ++m)
#pragma unroll
        for (int n = 0; n < NF; ++n) acc[m][n] = (f32x4){0.f, 0.f, 0.f, 0.f};

    const int nt = klen >> 6;
    stage(0, k0);
    if (nt > 1) stage(1, k0 + 64);
    for (int t = 0; t < nt; ++t) {
        if (t == nt - 1)              asm volatile("s_waitcnt vmcnt(0)" ::: "memory");
        else if constexpr (BN == 128) asm volatile("s_waitcnt vmcnt(8)" ::: "memory");
        else                          asm volatile("s_waitcnt vmcnt(7)" ::: "memory");
        __builtin_amdgcn_s_barrier();
        __builtin_amdgcn_sched_barrier(0);

        const char* Ab = (const char*)As + (t & 1) * TBA;
        const char* Bb = (const char*)Bs + (t & 1) * TBB;
        bf16x8 af[2][4], bfr[2][NF];
#pragma unroll
        for (int ks = 0; ks < 2; ++ks) {
#pragma unroll
            for (int m = 0; m < 4; ++m) {
                int row = wr * 64 + m * 16 + lrow;
                int psw = (((ks * 4 + kg) ^ (row & 7)) << 4);
                af[ks][m] = *(const bf16x8*)(Ab + row * 128 + psw);
            }
#pragma unroll
            for (int n = 0; n < NF; ++n) {
                int row = wc * (BN / 2) + n * 16 + lrow;
                int psw = (((ks * 4 + kg) ^ (row & 7)) << 4);
                bfr[ks][n] = *(const bf16x8*)(Bb + row * 128 + psw);
            }
        }
        __builtin_amdgcn_s_setprio(1);
#pragma unroll
        for (int ks = 0; ks < 2; ++ks)
#pragma unroll
            for (int m = 0; m < 4; ++m)
#pragma unroll
                for (int n = 0; n < NF; ++n)
                    acc[m][n] = __builtin_amdgcn_mfma_f32_16x16x32_bf16(af[ks][m], bfr[ks][n],
                                                                        acc[m][n], 0, 0, 0);
        __builtin_amdgcn_s_setprio(0);
        __builtin_amdgcn_s_barrier();
        if (t + 2 < nt) stage(t & 1, k0 + (t + 2) * 64);
    }

    const int rbase = tM + wr * 64 + ((lane >> 4) << 2);
    const int cbase = tN + wc * (BN / 2) + (lane & 15);
#pragma unroll
    for (int m = 0; m < 4; ++m) {
        int r0 = rbase + m * 16;
#pragma unroll
        for (int n = 0; n < NF; ++n) {
            int c = cbase + n * 16;
            if (EPI == 0) {
                if (c < 42) {
                    int b = r0 >> 12, node = r0 & 4095;
                    u32 lo = (u32)f2b(acc[m][n][0]) | ((u32)f2b(acc[m][n][1]) << 16);
                    u32 hi = (u32)f2b(acc[m][n][2]) | ((u32)f2b(acc[m][n][3]) << 16);
                    u32* dst = (u32*)(outFT + (size_t)(b * 42 + c) * 4096 + node);
                    dst[0] = lo; dst[1] = hi;
                } else {
#pragma unroll
                    for (int j = 0; j < 4; ++j)
                        outX[(size_t)(r0 + j) * 128 + c] = f2b(fmaxf(acc[m][n][j], 0.f));
                }
            } else if (EPI == 1) {
                if (c < 50) {
                    int b = r0 >> 12, node = r0 & 4095;
                    u32 lo = (u32)f2b(acc[m][n][0]) | ((u32)f2b(acc[m][n][1]) << 16);
                    u32 hi = (u32)f2b(acc[m][n][2]) | ((u32)f2b(acc[m][n][3]) << 16);
                    u32* dst = (u32*)(outFT + (size_t)(b * 50 + c) * 4096 + node);
                    dst[0] = lo; dst[1] = hi;
                }
            } else if (EPI == 4) {
                float v[4];
#pragma unroll
                for (int j = 0; j < 4; ++j) {
                    int lr = (r0 & 127) + j;
                    v[j] = acc[m][n][j] + aadd[c] + eadd[mil[lr] * 128 + c];
                }
                if (c < 42) {
                    int b = r0 >> 12, node = r0 & 4095;
                    u32 lo = (u32)f2b(v[0]) | ((u32)f2b(v[1]) << 16);
                    u32 hi = (u32)f2b(v[2]) | ((u32)f2b(v[3]) << 16);
                    u32* dst = (u32*)(outFT + (size_t)(b * 42 + c) * 4096 + node);
                    dst[0] = lo; dst[1] = hi;
                } else {
#pragma unroll
                    for (int j = 0; j < 4; ++j)
                        outX[(size_t)(r0 + j) * 128 + c] = f2b(fmaxf(v[j], 0.f));
                }
            } else {                      // EPI 6: split-K partial, f32
                if (c < ncol) {
                    float* P = outF32 + (size_t)blockIdx.z * ncol * 4096;
                    float4 v4 = {acc[m][n][0], acc[m][n][1], acc[m][n][2], acc[m][n][3]};
                    *(float4*)(P + (size_t)c * 4096 + r0) = v4;
                }
            }
        }
    }
}

// ------------------------------------------- split-K reduce + bias + relu -> X cols 0..41
// P layout [2][672][4096] f32. Block = (batch b, row tile rt): LDS transpose,
// write X rows (42 u16 = 21 dwords contiguous per row).

__global__ __launch_bounds__(256)
void reduce_lr(const float* __restrict__ P, const float* __restrict__ gb,
               u16* __restrict__ X) {
    __shared__ u16 stx[128 * 44];
    const int bx = blockIdx.x;
    const int b = bx >> 5, rt = bx & 31;
    const int r0 = rt * 128;
    const int tid = threadIdx.x;
    const int ci2 = tid >> 7, rr = tid & 127;
    const float* P1 = P + (size_t)672 * 4096;
#pragma unroll
    for (int q = 0; q < 21; ++q) {
        int ci = ci2 * 21 + q;
        size_t off = (size_t)(b * 42 + ci) * 4096 + r0 + rr;
        float v = P[off] + P1[off] + gb[ci];
        stx[rr * 44 + ci] = f2b(fmaxf(v, 0.f));
    }
    __syncthreads();
#pragma unroll
    for (int it = 0; it < 11; ++it) {
        int f = tid + it * 256;
        if (f < 2688) {
            int row = f / 21, col = f - row * 21;
            ((u32*)(X + (size_t)(((size_t)b << 12) + r0 + row) * 128))[col] =
                *((const u32*)stx + row * 22 + col);
        }
    }
}

// ---------------------------------------------------------------- final max (reduce both partials)

__global__ void max_reduce3(const float* __restrict__ P, const float* __restrict__ gb3,
                            float* __restrict__ out) {
    __shared__ float sred[256];
    int c = blockIdx.x;                   // 0..799 == b*50+l
    const float* p0 = P + (size_t)c * 4096;
    const float* p1 = P + (size_t)800 * 4096 + (size_t)c * 4096;
    float m = -1e30f;
    for (int i = threadIdx.x; i < 4096; i += 256) m = fmaxf(m, p0[i] + p1[i]);
    sred[threadIdx.x] = m;
    __syncthreads();
    for (int s = 128; s > 0; s >>= 1) {
        if (threadIdx.x < s) sred[threadIdx.x] = fmaxf(sred[threadIdx.x], sred[threadIdx.x + s]);
        __syncthreads();
    }
    if (threadIdx.x == 0) out[c] = sred[0] + gb3[c % 50];
}

// ---------------------------------------------------------------- launch

extern "C" void kernel_launch(void* const* d_in, const int* in_sizes, int n_in,
                              void* d_out, int out_size, void* d_ws, size_t ws_size,
                              hipStream_t stream) {
    const float* mask = (const float*)d_in[0];
    const float* mesh = (const float*)d_in[1];
    const int*   midx = (const int*)d_in[2];
    const float* adj  = (const float*)d_in[3];
    const float* aw1 = (const float*)d_in[4],  *ab1 = (const float*)d_in[5];
    const float* aw2 = (const float*)d_in[6],  *ab2 = (const float*)d_in[7];
    const float* aw3 = (const float*)d_in[8],  *ab3 = (const float*)d_in[9];
    const float* pw1 = (const float*)d_in[10], *pb1 = (const float*)d_in[11];
    const float* pw2 = (const float*)d_in[12], *pb2 = (const float*)d_in[13];
    const float* pw3 = (const float*)d_in[14], *pb3 = (const float*)d_in[15];
    const float* emb = (const float*)d_in[16];
    const float* gw0 = (const float*)d_in[17], *gb0 = (const float*)d_in[18];
    const float* gw1 = (const float*)d_in[19], *gb1 = (const float*)d_in[20];
    const float* gw2 = (const float*)d_in[21], *gb2 = (const float*)d_in[22];
    const float* gw3 = (const float*)d_in[23], *gb3 = (const float*)d_in[24];
    float* out = (float*)d_out;

    char* w = (char*)d_ws;
    u16*   adjB  = (u16*)(w);                    // 33,554,432
    u16*   H2R   = (u16*)(w + 33554432);         // 8,388,608
    float* P     = (float*)(w + 41943040);       // 2 x 800 x 4096 x 4 = 26,214,400
    u16*   X1    = (u16*)(w + 75497472);         // 16,777,216
    u16*   X2    = (u16*)(w + 92274688);         // 16,777,216
    u16*   FT    = (u16*)(w + 109051904);        // 896*4096*2 = 7,340,032
    u16*   gw1T  = (u16*)(w + 116391936);        // 32,768
    u16*   gw2T  = (u16*)(w + 116424704);        // 32,768
    u16*   gw3T  = (u16*)(w + 116457472);        // 32,768
    u16*   WpT   = (u16*)(w + 116490240);        // 16,384
    float* A2    = (float*)(w + 116506624);      // 8,192
    float* Ep    = (float*)(w + 116514816);      // 2,048
    float* aF    = (float*)(w + 116516864);      // 6,400

    // zero FT pad rows (672..895): padded GEMM B-tiles read zeros
    hipMemsetAsync(FT + (size_t)672 * 4096, 0, (size_t)(896 - 672) * 4096 * 2, stream);

    prep_weights<<<dim3(64), dim3(256), 0, stream>>>(gw1, gw2, gw3, gw1T, gw2T, gw3T);
    conv_adj<<<dim3(16384), dim3(256), 0, stream>>>(adj, adjB);
    action_mlp<<<dim3(16), dim3(256), 0, stream>>>(mask, aw1, ab1, aw2, ab2, aw3, ab3, aF);
    prep_fold<<<dim3(42), dim3(256), 0, stream>>>(aF, pb3, pw3, emb, gw0, A2, Ep, WpT);
    nf_h2r<<<dim3(1024), dim3(256), 0, stream>>>(mesh, pw1, pb1, pw2, pb2, H2R);

    // layer 0 (folded: K=64)
    gemm_bt<4, 128><<<dim3(512, 1, 1), dim3(256), 0, stream>>>(H2R, WpT, 64, 64,
        X1, FT, nullptr, A2, Ep, midx, 0);
    gemm_bt<6, 96><<<dim3(32, 8, 2), dim3(256), 0, stream>>>(adjB, FT, 4096, 2048,
        nullptr, nullptr, P, nullptr, nullptr, nullptr, 672);
    reduce_lr<<<dim3(512), dim3(256), 0, stream>>>(P, gb0, X1);
    // layer 1
    gemm_bt<0, 128><<<dim3(512, 1, 1), dim3(256), 0, stream>>>(X1, gw1T, 128, 128,
        X2, FT, nullptr, nullptr, nullptr, nullptr, 0);
    gemm_bt<6, 96><<<dim3(32, 8, 2), dim3(256), 0, stream>>>(adjB, FT, 4096, 2048,
        nullptr, nullptr, P, nullptr, nullptr, nullptr, 672);
    reduce_lr<<<dim3(512), dim3(256), 0, stream>>>(P, gb1, X2);
    // layer 2
    gemm_bt<0, 128><<<dim3(512, 1, 1), dim3(256), 0, stream>>>(X2, gw2T, 128, 128,
        X1, FT, nullptr, nullptr, nullptr, nullptr, 0);
    gemm_bt<6, 96><<<dim3(32, 8, 2), dim3(256), 0, stream>>>(adjB, FT, 4096, 2048,
        nullptr, nullptr, P, nullptr, nullptr, nullptr, 672);
    reduce_lr<<<dim3(512), dim3(256), 0, stream>>>(P, gb2, X1);
    // layer 3
    gemm_bt<1, 128><<<dim3(512, 1, 1), dim3(256), 0, stream>>>(X1, gw3T, 128, 128,
        nullptr, FT, nullptr, nullptr, nullptr, nullptr, 0);
    gemm_bt<6, 96><<<dim3(32, 9, 2), dim3(256), 0, stream>>>(adjB, FT, 4096, 2048,
        nullptr, nullptr, P, nullptr, nullptr, nullptr, 800);

    max_reduce3<<<dim3(800), dim3(256), 0, stream>>>(P, gb3, out);
}